// Round 1
// 528.151 us; speedup vs baseline: 1.1412x; 1.1412x over previous
//
#include <hip/hip_runtime.h>
#include <cfloat>

#define BB 64
#define NN 1024
#define MM 128
#define DD 256
#define MASKV (-1e30f)

typedef __attribute__((ext_vector_type(8))) short bf16x8;
typedef __attribute__((ext_vector_type(16))) float f32x16;

__device__ __forceinline__ unsigned short f2bf(float x) {
  union { float f; unsigned int u; } v; v.f = x;
  unsigned int r = v.u + 0x7fffu + ((v.u >> 16) & 1u);   // round-to-nearest-even
  return (unsigned short)(r >> 16);
}
__device__ __forceinline__ float bf2f(unsigned short h) {
  union { float f; unsigned int u; } v; v.u = ((unsigned int)h) << 16;
  return v.f;
}
__device__ __forceinline__ void split8(const float* xs, uint4* hv, uint4* lv) {
  unsigned hp[4], lp[4];
  #pragma unroll
  for (int p = 0; p < 4; p++) {
    unsigned short h0 = f2bf(xs[2 * p]), h1 = f2bf(xs[2 * p + 1]);
    unsigned short g0 = f2bf(xs[2 * p] - bf2f(h0));
    unsigned short g1 = f2bf(xs[2 * p + 1] - bf2f(h1));
    hp[p] = (unsigned)h0 | ((unsigned)h1 << 16);
    lp[p] = (unsigned)g0 | ((unsigned)g1 << 16);
  }
  *hv = make_uint4(hp[0], hp[1], hp[2], hp[3]);
  *lv = make_uint4(lp[0], lp[1], lp[2], lp[3]);
}

// ---------------------------------------------------------------------------
// K1: sub0[b,n] = c[b,n,:].w0 ; qtermM[b,m] = q[b,m,:].w1 + bias[m] + MASK*(1-qm)
// ---------------------------------------------------------------------------
__global__ __launch_bounds__(256) void k_dots(
    const float* __restrict__ c, const float* __restrict__ q,
    const int* __restrict__ qmask,
    const float* __restrict__ w0, const float* __restrict__ w1,
    const float* __restrict__ bias,
    float* __restrict__ sub0, float* __restrict__ qtermM) {
  int wave = (blockIdx.x * blockDim.x + threadIdx.x) >> 6;
  int lane = threadIdx.x & 63;
  const int total = BB * NN + BB * MM;
  if (wave >= total) return;
  const float* row;
  const float* w;
  if (wave < BB * NN) { row = c + (size_t)wave * DD; w = w0; }
  else                { row = q + (size_t)(wave - BB * NN) * DD; w = w1; }
  float4 v  = *(const float4*)(row + lane * 4);
  float4 wv = *(const float4*)(w   + lane * 4);
  float s = v.x * wv.x + v.y * wv.y + v.z * wv.z + v.w * wv.w;
  #pragma unroll
  for (int off = 32; off > 0; off >>= 1) s += __shfl_xor(s, off, 64);
  if (lane == 0) {
    if (wave < BB * NN) {
      sub0[wave] = s;
    } else {
      int r = wave - BB * NN;
      int m = r & (MM - 1);
      qtermM[r] = s + bias[m] + (qmask[r] ? 0.0f : MASKV);
    }
  }
}

// zero colsum (ws is poisoned 0xAA each call)
__global__ __launch_bounds__(256) void k_zero(float* __restrict__ p) {
  p[blockIdx.x * 256 + threadIdx.x] = 0.0f;
}

// ---------------------------------------------------------------------------
// K2 (MFMA): sub2 tile GEMM via bf16x3 split (hi*hi + hi*lo + lo*hi),
// 128n x 128m per block, K chunks of 64, mfma_f32_32x32x16_bf16.
// Fused row softmax (over m) -> S_, E = exp(sub2+sub0+mask), colsum atomics.
// LDS tiles are XOR-swizzled: byte = row*128 + ((k*2) ^ ((row&7)<<4)).
// acc C/D layout: col = lane&31, row = (reg&3) + 8*(reg>>2) + 4*(lane>>5).
// ---------------------------------------------------------------------------
__global__ __launch_bounds__(256) void k_score(
    const float* __restrict__ c, const float* __restrict__ q,
    const int* __restrict__ cmask, const float* __restrict__ wm,
    const float* __restrict__ sub0, const float* __restrict__ qtermM,
    float* __restrict__ S_, float* __restrict__ E,
    float* __restrict__ colsum) {
  __shared__ unsigned short cwh[128 * 64];   // 16 KB each, 64 KB total
  __shared__ unsigned short cwl[128 * 64];
  __shared__ unsigned short qhi[128 * 64];
  __shared__ unsigned short qlo[128 * 64];
  const int b = blockIdx.y;
  const int n0 = blockIdx.x * 128;
  const int t = threadIdx.x;
  const int w = t >> 6;          // wave id: n rows [w*32, w*32+32)
  const int l = t & 63;
  const int l31 = l & 31;
  const int lh = l >> 5;

  f32x16 acc[4];
  #pragma unroll
  for (int mb = 0; mb < 4; mb++)
    #pragma unroll
    for (int i = 0; i < 16; i++) acc[mb][i] = 0.0f;

  for (int k0 = 0; k0 < DD; k0 += 64) {
    __syncthreads();
    // stage cw (c*wm) and q, split to bf16 hi/lo, swizzled LDS writes.
    // 128 rows x 64 k each; thread stages 4 groups of 8 elems per tile.
    #pragma unroll
    for (int g = 0; g < 4; g++) {
      int lin = t + g * 256;           // 0..1023
      int row = lin >> 3;              // 0..127
      int kg  = (lin & 7) * 8;         // 0..56
      unsigned boff = (unsigned)(row * 128 + ((kg * 2) ^ ((row & 7) << 4)));
      float4 w0v = *(const float4*)(wm + k0 + kg);
      float4 w1v = *(const float4*)(wm + k0 + kg + 4);
      const float* cp = c + (size_t)(b * NN + n0 + row) * DD + k0 + kg;
      float4 a0 = *(const float4*)cp;
      float4 a1 = *(const float4*)(cp + 4);
      float xs[8] = {a0.x * w0v.x, a0.y * w0v.y, a0.z * w0v.z, a0.w * w0v.w,
                     a1.x * w1v.x, a1.y * w1v.y, a1.z * w1v.z, a1.w * w1v.w};
      uint4 hv, lv;
      split8(xs, &hv, &lv);
      *(uint4*)((char*)cwh + boff) = hv;
      *(uint4*)((char*)cwl + boff) = lv;
      const float* qp = q + (size_t)(b * MM + row) * DD + k0 + kg;
      float4 b0 = *(const float4*)qp;
      float4 b1 = *(const float4*)(qp + 4);
      float ys[8] = {b0.x, b0.y, b0.z, b0.w, b1.x, b1.y, b1.z, b1.w};
      split8(ys, &hv, &lv);
      *(uint4*)((char*)qhi + boff) = hv;
      *(uint4*)((char*)qlo + boff) = lv;
    }
    __syncthreads();
    // 4 k-steps of 16 within the chunk
    #pragma unroll
    for (int ks = 0; ks < 64; ks += 16) {
      int ak = ks + lh * 8;                        // 8 consecutive k per lane
      unsigned arow = (unsigned)(w * 32 + l31);
      unsigned aoff = arow * 128 + (((unsigned)(ak * 2)) ^ ((arow & 7) << 4));
      bf16x8 ah = *(const bf16x8*)((const char*)cwh + aoff);
      bf16x8 al = *(const bf16x8*)((const char*)cwl + aoff);
      #pragma unroll
      for (int mb = 0; mb < 4; mb++) {
        unsigned brow = (unsigned)(mb * 32 + l31);
        unsigned boff2 = brow * 128 + (((unsigned)(ak * 2)) ^ ((brow & 7) << 4));
        bf16x8 bh = *(const bf16x8*)((const char*)qhi + boff2);
        bf16x8 bl = *(const bf16x8*)((const char*)qlo + boff2);
        acc[mb] = __builtin_amdgcn_mfma_f32_32x32x16_bf16(ah, bh, acc[mb], 0, 0, 0);
        acc[mb] = __builtin_amdgcn_mfma_f32_32x32x16_bf16(ah, bl, acc[mb], 0, 0, 0);
        acc[mb] = __builtin_amdgcn_mfma_f32_32x32x16_bf16(al, bh, acc[mb], 0, 0, 0);
      }
    }
  }

  // fused row softmax + E + colsum
  float qt[4];
  #pragma unroll
  for (int mb = 0; mb < 4; mb++) qt[mb] = qtermM[b * MM + mb * 32 + l31];

  float ps[4] = {0.f, 0.f, 0.f, 0.f};
  #pragma unroll
  for (int r = 0; r < 16; r++) {
    int row = (r & 3) + 8 * (r >> 2) + 4 * lh;    // 0..31 within wave tile
    int gn = n0 + w * 32 + row;
    float s0m = sub0[b * NN + gn] + (cmask[b * NN + gn] ? 0.0f : MASKV);
    float x[4];
    float vmax = -FLT_MAX;
    #pragma unroll
    for (int mb = 0; mb < 4; mb++) { x[mb] = acc[mb][r] + qt[mb]; vmax = fmaxf(vmax, x[mb]); }
    #pragma unroll
    for (int off = 16; off > 0; off >>= 1) vmax = fmaxf(vmax, __shfl_xor(vmax, off, 64));
    float e[4];
    float vsum = 0.0f;
    #pragma unroll
    for (int mb = 0; mb < 4; mb++) { e[mb] = __expf(x[mb] - vmax); vsum += e[mb]; }
    #pragma unroll
    for (int off = 16; off > 0; off >>= 1) vsum += __shfl_xor(vsum, off, 64);
    float inv = 1.0f / vsum;
    size_t base = (size_t)(b * NN + gn) * MM + l31;
    #pragma unroll
    for (int mb = 0; mb < 4; mb++) {
      S_[base + mb * 32] = e[mb] * inv;
      float Ev = __expf(acc[mb][r] + s0m);   // exp(-1e30+x) underflows to 0 exactly
      E[base + mb * 32] = Ev;
      ps[mb] += Ev;
    }
  }
  #pragma unroll
  for (int mb = 0; mb < 4; mb++) {
    ps[mb] += __shfl_xor(ps[mb], 32, 64);    // combine the two half-wave row sets
    if (lh == 0) atomicAdd(&colsum[b * MM + mb * 32 + l31], ps[mb]);
  }
}

// ---------------------------------------------------------------------------
// K4: A[b,m,d] = (sum_n E[b,n,m] * c[b,n,d]) / colsum[b,m]
// ---------------------------------------------------------------------------
__global__ __launch_bounds__(256) void k_colA(
    const float* __restrict__ E, const float* __restrict__ c,
    const float* __restrict__ colsum, float* __restrict__ A) {
  __shared__ float se[32 * 64];   // [nk][m]
  __shared__ float sc[32 * 64];   // [nk][d]
  const int b = blockIdx.z;
  const int m0 = blockIdx.x * 64;
  const int d0 = blockIdx.y * 64;
  const int t = threadIdx.x;
  const int tx = t & 15;          // d group
  const int ty = t >> 4;          // m group
  const int lr = t >> 4;          // staging row (0..15), +16 for second half
  const int lc = (t & 15) * 4;    // staging col

  const float* Eb = E + (size_t)b * NN * MM + m0 + lc;
  const float* cb = c + (size_t)b * NN * DD + d0 + lc;

  float4 ev0 = *(const float4*)(Eb + (size_t)lr * MM);
  float4 ev1 = *(const float4*)(Eb + (size_t)(16 + lr) * MM);
  float4 cv0 = *(const float4*)(cb + (size_t)lr * DD);
  float4 cv1 = *(const float4*)(cb + (size_t)(16 + lr) * DD);

  float acc[4][4];
  #pragma unroll
  for (int mi = 0; mi < 4; mi++)
    #pragma unroll
    for (int di = 0; di < 4; di++) acc[mi][di] = 0.0f;

  for (int n0 = 0; n0 < NN; n0 += 32) {
    *(float4*)(&se[lr * 64 + lc])        = ev0;
    *(float4*)(&se[(16 + lr) * 64 + lc]) = ev1;
    *(float4*)(&sc[lr * 64 + lc])        = cv0;
    *(float4*)(&sc[(16 + lr) * 64 + lc]) = cv1;
    __syncthreads();
    if (n0 + 32 < NN) {
      int nn = n0 + 32;
      ev0 = *(const float4*)(Eb + (size_t)(nn + lr) * MM);
      ev1 = *(const float4*)(Eb + (size_t)(nn + 16 + lr) * MM);
      cv0 = *(const float4*)(cb + (size_t)(nn + lr) * DD);
      cv1 = *(const float4*)(cb + (size_t)(nn + 16 + lr) * DD);
    }
    #pragma unroll
    for (int kk = 0; kk < 32; kk++) {
      float4 e4 = *(const float4*)(&se[kk * 64 + ty * 4]);
      float4 c4 = *(const float4*)(&sc[kk * 64 + tx * 4]);
      float em[4] = {e4.x, e4.y, e4.z, e4.w};
      float cd[4] = {c4.x, c4.y, c4.z, c4.w};
      #pragma unroll
      for (int mi = 0; mi < 4; mi++)
        #pragma unroll
        for (int di = 0; di < 4; di++) acc[mi][di] += em[mi] * cd[di];
    }
    __syncthreads();
  }

  #pragma unroll
  for (int mi = 0; mi < 4; mi++) {
    int m = m0 + ty * 4 + mi;
    float inv = 1.0f / colsum[b * MM + m];
    float4 o = make_float4(acc[mi][0] * inv, acc[mi][1] * inv,
                           acc[mi][2] * inv, acc[mi][3] * inv);
    *(float4*)(A + (size_t)(b * MM + m) * DD + d0 + tx * 4) = o;
  }
}

// ---------------------------------------------------------------------------
// K5: c2q = S_ @ q ; q2c = S_ @ A ; out = [c, c2q, c*c2q, c*q2c]
// ---------------------------------------------------------------------------
__global__ __launch_bounds__(256) void k_out(
    const float* __restrict__ c, const float* __restrict__ q,
    const float* __restrict__ S_, const float* __restrict__ A,
    float* __restrict__ out) {
  __shared__ float s[32 * 128];
  const int b = blockIdx.y;
  const int n0 = blockIdx.x * 32;
  const int t = threadIdx.x;
  const int dx = t & 63, ry = t >> 6;  // ry = wave id

  size_t sbase = (size_t)(b * NN + n0) * MM;
  #pragma unroll
  for (int it = 0; it < 16; it++) {
    int idx = t + it * 256;
    s[idx] = S_[sbase + idx];
  }
  __syncthreads();

  float c2q[8][4], q2c[8][4];
  #pragma unroll
  for (int i = 0; i < 8; i++)
    #pragma unroll
    for (int k = 0; k < 4; k++) { c2q[i][k] = 0.f; q2c[i][k] = 0.f; }

  for (int m = 0; m < MM; m++) {
    float4 qv = *(const float4*)(q + (size_t)(b * MM + m) * DD + dx * 4);
    float4 av = *(const float4*)(A + (size_t)(b * MM + m) * DD + dx * 4);
    #pragma unroll
    for (int i = 0; i < 8; i++) {
      float sv = s[(ry * 8 + i) * 128 + m];
      c2q[i][0] += sv * qv.x; c2q[i][1] += sv * qv.y;
      c2q[i][2] += sv * qv.z; c2q[i][3] += sv * qv.w;
      q2c[i][0] += sv * av.x; q2c[i][1] += sv * av.y;
      q2c[i][2] += sv * av.z; q2c[i][3] += sv * av.w;
    }
  }

  #pragma unroll
  for (int i = 0; i < 8; i++) {
    int gn = n0 + ry * 8 + i;
    float4 cv = *(const float4*)(c + (size_t)(b * NN + gn) * DD + dx * 4);
    size_t ob = (size_t)(b * NN + gn) * (4 * DD) + dx * 4;
    float4 o1 = make_float4(c2q[i][0], c2q[i][1], c2q[i][2], c2q[i][3]);
    float4 o2 = make_float4(cv.x * o1.x, cv.y * o1.y, cv.z * o1.z, cv.w * o1.w);
    float4 o3 = make_float4(cv.x * q2c[i][0], cv.y * q2c[i][1],
                            cv.z * q2c[i][2], cv.w * q2c[i][3]);
    *(float4*)(out + ob)            = cv;
    *(float4*)(out + ob + DD)       = o1;
    *(float4*)(out + ob + 2 * DD)   = o2;
    *(float4*)(out + ob + 3 * DD)   = o3;
  }
}

// ---------------------------------------------------------------------------
extern "C" void kernel_launch(void* const* d_in, const int* in_sizes, int n_in,
                              void* d_out, int out_size, void* d_ws, size_t ws_size,
                              hipStream_t stream) {
  const float* c     = (const float*)d_in[0];
  const float* q     = (const float*)d_in[1];
  const int*   cmask = (const int*)d_in[2];
  const int*   qmask = (const int*)d_in[3];
  const float* w0    = (const float*)d_in[4];
  const float* w1    = (const float*)d_in[5];
  const float* wm    = (const float*)d_in[6];
  const float* bias  = (const float*)d_in[7];
  float* out = (float*)d_out;
  float* ws  = (float*)d_ws;

  float* S_     = ws;                  // B*N*M = 8388608
  float* E      = ws + 8388608;        // B*N*M
  float* A      = ws + 16777216;       // B*M*D = 2097152
  float* sub0   = ws + 18874368;       // B*N   = 65536
  float* qtermM = ws + 18939904;       // B*M   = 8192
  float* colsum = ws + 18948096;       // B*M   = 8192

  k_dots<<<18432, 256, 0, stream>>>(c, q, qmask, w0, w1, bias, sub0, qtermM);
  k_zero<<<32, 256, 0, stream>>>(colsum);
  k_score<<<dim3(8, BB), 256, 0, stream>>>(c, q, cmask, wm, sub0, qtermM, S_, E, colsum);
  k_colA<<<dim3(2, 4, BB), 256, 0, stream>>>(E, c, colsum, A);
  k_out<<<dim3(32, BB), 256, 0, stream>>>(c, q, S_, A, out);
}

// Round 2
// 509.107 us; speedup vs baseline: 1.1839x; 1.0374x over previous
//
#include <hip/hip_runtime.h>
#include <cfloat>

#define BB 64
#define NN 1024
#define MM 128
#define DD 256
#define MASKV (-1e30f)

typedef __attribute__((ext_vector_type(8))) short bf16x8;
typedef __attribute__((ext_vector_type(16))) float f32x16;

__device__ __forceinline__ unsigned short f2bf(float x) {
  union { float f; unsigned int u; } v; v.f = x;
  unsigned int r = v.u + 0x7fffu + ((v.u >> 16) & 1u);   // round-to-nearest-even
  return (unsigned short)(r >> 16);
}
__device__ __forceinline__ float bf2f(unsigned short h) {
  union { float f; unsigned int u; } v; v.u = ((unsigned int)h) << 16;
  return v.f;
}
__device__ __forceinline__ void split8(const float* xs, uint4* hv, uint4* lv) {
  unsigned hp[4], lp[4];
  #pragma unroll
  for (int p = 0; p < 4; p++) {
    unsigned short h0 = f2bf(xs[2 * p]), h1 = f2bf(xs[2 * p + 1]);
    unsigned short g0 = f2bf(xs[2 * p] - bf2f(h0));
    unsigned short g1 = f2bf(xs[2 * p + 1] - bf2f(h1));
    hp[p] = (unsigned)h0 | ((unsigned)h1 << 16);
    lp[p] = (unsigned)g0 | ((unsigned)g1 << 16);
  }
  *hv = make_uint4(hp[0], hp[1], hp[2], hp[3]);
  *lv = make_uint4(lp[0], lp[1], lp[2], lp[3]);
}
__device__ __forceinline__ bf16x8 u2b(uint4 u) {
  union { uint4 a; bf16x8 b; } x; x.a = u; return x.b;
}

// ---------------------------------------------------------------------------
// K1: sub0[b,n] = c[b,n,:].w0 ; qtermM[b,m] = q[b,m,:].w1 + bias[m] + MASK*(1-qm)
// ---------------------------------------------------------------------------
__global__ __launch_bounds__(256) void k_dots(
    const float* __restrict__ c, const float* __restrict__ q,
    const int* __restrict__ qmask,
    const float* __restrict__ w0, const float* __restrict__ w1,
    const float* __restrict__ bias,
    float* __restrict__ sub0, float* __restrict__ qtermM) {
  int wave = (blockIdx.x * blockDim.x + threadIdx.x) >> 6;
  int lane = threadIdx.x & 63;
  const int total = BB * NN + BB * MM;
  if (wave >= total) return;
  const float* row;
  const float* w;
  if (wave < BB * NN) { row = c + (size_t)wave * DD; w = w0; }
  else                { row = q + (size_t)(wave - BB * NN) * DD; w = w1; }
  float4 v  = *(const float4*)(row + lane * 4);
  float4 wv = *(const float4*)(w   + lane * 4);
  float s = v.x * wv.x + v.y * wv.y + v.z * wv.z + v.w * wv.w;
  #pragma unroll
  for (int off = 32; off > 0; off >>= 1) s += __shfl_xor(s, off, 64);
  if (lane == 0) {
    if (wave < BB * NN) {
      sub0[wave] = s;
    } else {
      int r = wave - BB * NN;
      int m = r & (MM - 1);
      qtermM[r] = s + bias[m] + (qmask[r] ? 0.0f : MASKV);
    }
  }
}

// zero colsum (ws is poisoned 0xAA each call)
__global__ __launch_bounds__(256) void k_zero(float* __restrict__ p) {
  p[blockIdx.x * 256 + threadIdx.x] = 0.0f;
}

// ---------------------------------------------------------------------------
// K2 (MFMA): sub2 tile GEMM via bf16x3 split (hi*hi + hi*lo + lo*hi),
// 128n x 128m per block, K chunks of 64, mfma_f32_32x32x16_bf16.
// Fused row softmax (over m) -> S_, E = exp(sub2+sub0+mask), colsum atomics.
// LDS tiles are XOR-swizzled: byte = row*128 + ((k*2) ^ ((row&7)<<4)).
// acc C/D layout: col = lane&31, row = (reg&3) + 8*(reg>>2) + 4*(lane>>5).
// ---------------------------------------------------------------------------
__global__ __launch_bounds__(256) void k_score(
    const float* __restrict__ c, const float* __restrict__ q,
    const int* __restrict__ cmask, const float* __restrict__ wm,
    const float* __restrict__ sub0, const float* __restrict__ qtermM,
    float* __restrict__ S_, float* __restrict__ E,
    float* __restrict__ colsum) {
  __shared__ unsigned short cwh[128 * 64];   // 16 KB each, 64 KB total
  __shared__ unsigned short cwl[128 * 64];
  __shared__ unsigned short qhi[128 * 64];
  __shared__ unsigned short qlo[128 * 64];
  const int b = blockIdx.y;
  const int n0 = blockIdx.x * 128;
  const int t = threadIdx.x;
  const int w = t >> 6;          // wave id: n rows [w*32, w*32+32)
  const int l = t & 63;
  const int l31 = l & 31;
  const int lh = l >> 5;

  f32x16 acc[4];
  #pragma unroll
  for (int mb = 0; mb < 4; mb++)
    #pragma unroll
    for (int i = 0; i < 16; i++) acc[mb][i] = 0.0f;

  for (int k0 = 0; k0 < DD; k0 += 64) {
    __syncthreads();
    #pragma unroll
    for (int g = 0; g < 4; g++) {
      int lin = t + g * 256;           // 0..1023
      int row = lin >> 3;              // 0..127
      int kg  = (lin & 7) * 8;         // 0..56
      unsigned boff = (unsigned)(row * 128 + ((kg * 2) ^ ((row & 7) << 4)));
      float4 w0v = *(const float4*)(wm + k0 + kg);
      float4 w1v = *(const float4*)(wm + k0 + kg + 4);
      const float* cp = c + (size_t)(b * NN + n0 + row) * DD + k0 + kg;
      float4 a0 = *(const float4*)cp;
      float4 a1 = *(const float4*)(cp + 4);
      float xs[8] = {a0.x * w0v.x, a0.y * w0v.y, a0.z * w0v.z, a0.w * w0v.w,
                     a1.x * w1v.x, a1.y * w1v.y, a1.z * w1v.z, a1.w * w1v.w};
      uint4 hv, lv;
      split8(xs, &hv, &lv);
      *(uint4*)((char*)cwh + boff) = hv;
      *(uint4*)((char*)cwl + boff) = lv;
      const float* qp = q + (size_t)(b * MM + row) * DD + k0 + kg;
      float4 b0 = *(const float4*)qp;
      float4 b1 = *(const float4*)(qp + 4);
      float ys[8] = {b0.x, b0.y, b0.z, b0.w, b1.x, b1.y, b1.z, b1.w};
      split8(ys, &hv, &lv);
      *(uint4*)((char*)qhi + boff) = hv;
      *(uint4*)((char*)qlo + boff) = lv;
    }
    __syncthreads();
    #pragma unroll
    for (int ks = 0; ks < 64; ks += 16) {
      int ak = ks + lh * 8;                        // 8 consecutive k per lane
      unsigned arow = (unsigned)(w * 32 + l31);
      unsigned aoff = arow * 128 + (((unsigned)(ak * 2)) ^ ((arow & 7) << 4));
      bf16x8 ah = *(const bf16x8*)((const char*)cwh + aoff);
      bf16x8 al = *(const bf16x8*)((const char*)cwl + aoff);
      #pragma unroll
      for (int mb = 0; mb < 4; mb++) {
        unsigned brow = (unsigned)(mb * 32 + l31);
        unsigned boff2 = brow * 128 + (((unsigned)(ak * 2)) ^ ((brow & 7) << 4));
        bf16x8 bh = *(const bf16x8*)((const char*)qhi + boff2);
        bf16x8 bl = *(const bf16x8*)((const char*)qlo + boff2);
        acc[mb] = __builtin_amdgcn_mfma_f32_32x32x16_bf16(ah, bh, acc[mb], 0, 0, 0);
        acc[mb] = __builtin_amdgcn_mfma_f32_32x32x16_bf16(ah, bl, acc[mb], 0, 0, 0);
        acc[mb] = __builtin_amdgcn_mfma_f32_32x32x16_bf16(al, bh, acc[mb], 0, 0, 0);
      }
    }
  }

  // fused row softmax + E + colsum
  float qt[4];
  #pragma unroll
  for (int mb = 0; mb < 4; mb++) qt[mb] = qtermM[b * MM + mb * 32 + l31];

  float ps[4] = {0.f, 0.f, 0.f, 0.f};
  #pragma unroll
  for (int r = 0; r < 16; r++) {
    int row = (r & 3) + 8 * (r >> 2) + 4 * lh;    // 0..31 within wave tile
    int gn = n0 + w * 32 + row;
    float s0m = sub0[b * NN + gn] + (cmask[b * NN + gn] ? 0.0f : MASKV);
    float x[4];
    float vmax = -FLT_MAX;
    #pragma unroll
    for (int mb = 0; mb < 4; mb++) { x[mb] = acc[mb][r] + qt[mb]; vmax = fmaxf(vmax, x[mb]); }
    #pragma unroll
    for (int off = 16; off > 0; off >>= 1) vmax = fmaxf(vmax, __shfl_xor(vmax, off, 64));
    float e[4];
    float vsum = 0.0f;
    #pragma unroll
    for (int mb = 0; mb < 4; mb++) { e[mb] = __expf(x[mb] - vmax); vsum += e[mb]; }
    #pragma unroll
    for (int off = 16; off > 0; off >>= 1) vsum += __shfl_xor(vsum, off, 64);
    float inv = 1.0f / vsum;
    size_t base = (size_t)(b * NN + gn) * MM + l31;
    #pragma unroll
    for (int mb = 0; mb < 4; mb++) {
      S_[base + mb * 32] = e[mb] * inv;
      float Ev = __expf(acc[mb][r] + s0m);   // exp(-1e30+x) underflows to 0 exactly
      E[base + mb * 32] = Ev;
      ps[mb] += Ev;
    }
  }
  #pragma unroll
  for (int mb = 0; mb < 4; mb++) {
    ps[mb] += __shfl_xor(ps[mb], 32, 64);    // combine the two half-wave row sets
    if (lh == 0) atomicAdd(&colsum[b * MM + mb * 32 + l31], ps[mb]);
  }
}

// ---------------------------------------------------------------------------
// K4: A[b,m,d] = (sum_n E[b,n,m] * c[b,n,d]) / colsum[b,m]
// ---------------------------------------------------------------------------
__global__ __launch_bounds__(256) void k_colA(
    const float* __restrict__ E, const float* __restrict__ c,
    const float* __restrict__ colsum, float* __restrict__ A) {
  __shared__ float se[32 * 64];   // [nk][m]
  __shared__ float sc[32 * 64];   // [nk][d]
  const int b = blockIdx.z;
  const int m0 = blockIdx.x * 64;
  const int d0 = blockIdx.y * 64;
  const int t = threadIdx.x;
  const int tx = t & 15;          // d group
  const int ty = t >> 4;          // m group
  const int lr = t >> 4;          // staging row (0..15), +16 for second half
  const int lc = (t & 15) * 4;    // staging col

  const float* Eb = E + (size_t)b * NN * MM + m0 + lc;
  const float* cb = c + (size_t)b * NN * DD + d0 + lc;

  float4 ev0 = *(const float4*)(Eb + (size_t)lr * MM);
  float4 ev1 = *(const float4*)(Eb + (size_t)(16 + lr) * MM);
  float4 cv0 = *(const float4*)(cb + (size_t)lr * DD);
  float4 cv1 = *(const float4*)(cb + (size_t)(16 + lr) * DD);

  float acc[4][4];
  #pragma unroll
  for (int mi = 0; mi < 4; mi++)
    #pragma unroll
    for (int di = 0; di < 4; di++) acc[mi][di] = 0.0f;

  for (int n0 = 0; n0 < NN; n0 += 32) {
    *(float4*)(&se[lr * 64 + lc])        = ev0;
    *(float4*)(&se[(16 + lr) * 64 + lc]) = ev1;
    *(float4*)(&sc[lr * 64 + lc])        = cv0;
    *(float4*)(&sc[(16 + lr) * 64 + lc]) = cv1;
    __syncthreads();
    if (n0 + 32 < NN) {
      int nn = n0 + 32;
      ev0 = *(const float4*)(Eb + (size_t)(nn + lr) * MM);
      ev1 = *(const float4*)(Eb + (size_t)(nn + 16 + lr) * MM);
      cv0 = *(const float4*)(cb + (size_t)(nn + lr) * DD);
      cv1 = *(const float4*)(cb + (size_t)(nn + 16 + lr) * DD);
    }
    #pragma unroll
    for (int kk = 0; kk < 32; kk++) {
      float4 e4 = *(const float4*)(&se[kk * 64 + ty * 4]);
      float4 c4 = *(const float4*)(&sc[kk * 64 + tx * 4]);
      float em[4] = {e4.x, e4.y, e4.z, e4.w};
      float cd[4] = {c4.x, c4.y, c4.z, c4.w};
      #pragma unroll
      for (int mi = 0; mi < 4; mi++)
        #pragma unroll
        for (int di = 0; di < 4; di++) acc[mi][di] += em[mi] * cd[di];
    }
    __syncthreads();
  }

  #pragma unroll
  for (int mi = 0; mi < 4; mi++) {
    int m = m0 + ty * 4 + mi;
    float inv = 1.0f / colsum[b * MM + m];
    float4 o = make_float4(acc[mi][0] * inv, acc[mi][1] * inv,
                           acc[mi][2] * inv, acc[mi][3] * inv);
    *(float4*)(A + (size_t)(b * MM + m) * DD + d0 + tx * 4) = o;
  }
}

// ---------------------------------------------------------------------------
// K5 (MFMA): c2q = S_ @ q ; q2c = S_ @ A ; out = [c, c2q, c*c2q, c*q2c]
// K = M = 128. No LDS: fragments built straight from global (q/A/S_ slices are
// L2-resident), bf16x3 split, mfma_f32_32x32x16_bf16.
// Block = 512 thr = 8 waves. Waves 0-3: c2q + planes {c, c2q, c*c2q};
// waves 4-7: q2c + plane {c*q2c}. Per wave: 1 n-frag (nf=wi&1), 4 d-frags
// (fd0=(wi>>1)*4), acc = 4 x f32x16.
// A-frag (S_): lane holds row n=l31, k=lh*8+j consecutive -> 2x dwordx4.
// B-frag (q/A): lane holds col d=l31, k=lh*8+j -> 8 stride-DD dword loads
// (imm offsets j*1024B), L2 hits.
// ---------------------------------------------------------------------------
__global__ __launch_bounds__(512) void k_out(
    const float* __restrict__ c, const float* __restrict__ q,
    const float* __restrict__ S_, const float* __restrict__ A,
    float* __restrict__ out) {
  const int b = blockIdx.y;
  const int n0 = blockIdx.x * 64;
  const int t = threadIdx.x;
  const int w = t >> 6;            // 0..7
  const int l = t & 63;
  const int l31 = l & 31;
  const int lh = l >> 5;
  const int grp = w >> 2;          // 0: c2q, 1: q2c
  const int wi = w & 3;
  const int nf = wi & 1;           // n-frag (32 rows)
  const int fd0 = (wi >> 1) * 4;   // first d-frag (of 8)

  const float* Bsrc = grp ? A : q;

  f32x16 acc[4];
  #pragma unroll
  for (int df = 0; df < 4; df++)
    #pragma unroll
    for (int i = 0; i < 16; i++) acc[df][i] = 0.0f;

  const float* srow = S_ + (size_t)(b * NN + n0 + nf * 32 + l31) * MM + lh * 8;
  const float* bbase = Bsrc + (size_t)(b * MM + lh * 8) * DD + l31;

  #pragma unroll 2
  for (int ks = 0; ks < 8; ks++) {
    // A-frag: S_[n][m], 8 consecutive m per lane
    float4 s0 = *(const float4*)(srow + ks * 16);
    float4 s1 = *(const float4*)(srow + ks * 16 + 4);
    float xs[8] = {s0.x, s0.y, s0.z, s0.w, s1.x, s1.y, s1.z, s1.w};
    uint4 hv, lv;
    split8(xs, &hv, &lv);
    bf16x8 ah = u2b(hv), al = u2b(lv);
    #pragma unroll
    for (int df = 0; df < 4; df++) {
      const float* bp = bbase + (size_t)(ks * 16) * DD + (fd0 + df) * 32;
      float ys[8];
      #pragma unroll
      for (int j = 0; j < 8; j++) ys[j] = bp[j * DD];
      split8(ys, &hv, &lv);
      bf16x8 bh = u2b(hv), bl = u2b(lv);
      acc[df] = __builtin_amdgcn_mfma_f32_32x32x16_bf16(ah, bh, acc[df], 0, 0, 0);
      acc[df] = __builtin_amdgcn_mfma_f32_32x32x16_bf16(ah, bl, acc[df], 0, 0, 0);
      acc[df] = __builtin_amdgcn_mfma_f32_32x32x16_bf16(al, bh, acc[df], 0, 0, 0);
    }
  }

  // epilogue: C/D layout col=l31 (d), row=(r&3)+8*(r>>2)+4*lh (n within frag)
  #pragma unroll
  for (int df = 0; df < 4; df++) {
    int d = (fd0 + df) * 32 + l31;
    #pragma unroll
    for (int r = 0; r < 16; r++) {
      int row = (r & 3) + 8 * (r >> 2) + 4 * lh;
      int gn = n0 + nf * 32 + row;
      float v = acc[df][r];
      float cv = c[(size_t)(b * NN + gn) * DD + d];
      size_t ob = (size_t)(b * NN + gn) * (4 * DD) + d;
      if (grp == 0) {
        out[ob]            = cv;
        out[ob + DD]       = v;
        out[ob + 2 * DD]   = cv * v;
      } else {
        out[ob + 3 * DD]   = cv * v;
      }
    }
  }
}

// ---------------------------------------------------------------------------
extern "C" void kernel_launch(void* const* d_in, const int* in_sizes, int n_in,
                              void* d_out, int out_size, void* d_ws, size_t ws_size,
                              hipStream_t stream) {
  const float* c     = (const float*)d_in[0];
  const float* q     = (const float*)d_in[1];
  const int*   cmask = (const int*)d_in[2];
  const int*   qmask = (const int*)d_in[3];
  const float* w0    = (const float*)d_in[4];
  const float* w1    = (const float*)d_in[5];
  const float* wm    = (const float*)d_in[6];
  const float* bias  = (const float*)d_in[7];
  float* out = (float*)d_out;
  float* ws  = (float*)d_ws;

  float* S_     = ws;                  // B*N*M = 8388608
  float* E      = ws + 8388608;        // B*N*M
  float* A      = ws + 16777216;       // B*M*D = 2097152
  float* sub0   = ws + 18874368;       // B*N   = 65536
  float* qtermM = ws + 18939904;       // B*M   = 8192
  float* colsum = ws + 18948096;       // B*M   = 8192

  k_dots<<<18432, 256, 0, stream>>>(c, q, qmask, w0, w1, bias, sub0, qtermM);
  k_zero<<<32, 256, 0, stream>>>(colsum);
  k_score<<<dim3(8, BB), 256, 0, stream>>>(c, q, cmask, wm, sub0, qtermM, S_, E, colsum);
  k_colA<<<dim3(2, 4, BB), 256, 0, stream>>>(E, c, colsum, A);
  k_out<<<dim3(16, BB), 512, 0, stream>>>(c, q, S_, A, out);
}